// Round 7
// baseline (590.283 us; speedup 1.0000x reference)
//
#include <hip/hip_runtime.h>

typedef unsigned short u16;
typedef unsigned int u32;
typedef __attribute__((ext_vector_type(8))) short short8;
typedef __attribute__((ext_vector_type(4))) short short4v;
typedef __attribute__((ext_vector_type(4))) float floatx4;

#define HH 128
#define WW 128
#define XP 72   // u16 pitch of px-major LDS tile (144 B, b128-aligned)

__device__ __forceinline__ float bf2f(u16 u) {
    u32 b = ((u32)u) << 16;
    return __builtin_bit_cast(float, b);
}
__device__ __forceinline__ u16 f2bf(float f) {
    u32 b = __builtin_bit_cast(u32, f);
    b += 0x7FFFu + ((b >> 16) & 1u);
    return (u16)(b >> 16);
}

typedef __attribute__((address_space(3))) u16 lds_u16;
typedef const __attribute__((address_space(1))) u16 glob_u16;
__device__ __forceinline__ void gl_lds16(const u16* g, u16* l) {
    __builtin_amdgcn_global_load_lds((glob_u16*)g, (lds_u16*)l, 16, 0, 0);
}

// ws layout (bytes):
//   [0,4)                 flag: 1 = fp32 inputs, 0 = bf16 inputs
//   [256, +204800)        w5c  bf16 A-frag (50 ks * 2048): composite 5x5 weights
//   [205056, +3072)       scal fp32: biasC[64], wr[640], b3[64]
//   [208128, +1064960)    V    fp32 [b][4][130][64]: virtual y3 frame values
//                         (8*4*130*64*4 = 1064960 B — r6 bug: had 851968, V
//                          overlapped xt and poisoned it with fp32 bits)
//   [1273088, +16777216)  xt   bf16 [b][h][w][ic]
#define W5C_BYTE 256
#define SCAL_BYTE 205056
#define V_BYTE 208128
#define XT_BYTE 1273088
#define N_W5C 102400
#define N_SCAL 768
#define PACK_N (N_W5C + N_SCAL)

__global__ __launch_bounds__(256) void sniff_kernel(const u16* __restrict__ xu,
                                                    int* __restrict__ flag) {
    __shared__ int cnt;
    if (threadIdx.x == 0) cnt = 0;
    __syncthreads();
    int c = 0;
    for (int k = 0; k < 8; ++k) {
        int idx = 2 * (threadIdx.x * 8 + k);
        u16 u = xu[idx];
        int e = (u >> 7) & 0xFF;
        if (e >= 140) c++;
    }
    atomicAdd(&cnt, c);
    __syncthreads();
    if (threadIdx.x == 0) *flag = (cnt >= 8) ? 1 : 0;
}

__device__ __forceinline__ float load_any(const void* p, int i, int isf32) {
    return isf32 ? ((const float*)p)[i] : bf2f(((const u16*)p)[i]);
}

// Composite weights in MFMA A-frag order:
// elem = ks*2048 + mt*512 + lane*8 + j holds A[oc=mt*16+(lane&15)][k],
// k = ks*32 + ((lane>>4)&3)*8 + j = tap*64 + ic, tap = kh*5+kw.
// W5c[oc][ic][kh][kw] = wr0*w5[kh][kw] + sum_{sh,sw} wr[1+3sh+sw]*w3[r][c]
//   with r = (kh-2)+sw, c = (kw-2)+sh (when in [0,3)).
__global__ __launch_bounds__(256) void prepack(
        const void* w3, const void* b3, const void* w5, const void* b5,
        const void* wr, const void* br, const int* __restrict__ flag,
        u16* __restrict__ w5c, float* __restrict__ scal) {
    int i = blockIdx.x * 256 + threadIdx.x;
    if (i >= PACK_N) return;
    int f = *flag;
    if (i < N_W5C) {
        int j = i & 7, lane = (i >> 3) & 63, mt = (i >> 9) & 3, ks = i >> 11;
        int oc = mt * 16 + (lane & 15);
        int k = ks * 32 + ((lane >> 4) & 3) * 8 + j;
        int tap = k >> 6, ic = k & 63;
        int kh = tap / 5, kw = tap - kh * 5;
        int dh = kh - 2, dw = kw - 2;
        float v = load_any(wr, oc * 10, f) * load_any(w5, (oc * 64 + ic) * 25 + tap, f);
        for (int sw = 0; sw < 3; ++sw) {
            int r = dh + sw;
            if (r < 0 || r > 2) continue;
            for (int sh = 0; sh < 3; ++sh) {
                int c = dw + sh;
                if (c < 0 || c > 2) continue;
                v += load_any(wr, oc * 10 + 1 + sh * 3 + sw, f) *
                     load_any(w3, (oc * 64 + ic) * 9 + r * 3 + c, f);
            }
        }
        w5c[i] = f2bf(v);
    } else {
        int i2 = i - N_W5C;
        float v;
        if (i2 < 64) {          // biasC
            int oc = i2;
            float swr = 0.f;
            for (int g = 1; g <= 9; ++g) swr += load_any(wr, oc * 10 + g, f);
            v = load_any(wr, oc * 10, f) * load_any(b5, oc, f) +
                swr * load_any(b3, oc, f) + load_any(br, oc, f);
        } else if (i2 < 704) {  // wr copy
            v = load_any(wr, i2 - 64, f);
        } else {                // b3 copy
            v = load_any(b3, i2 - 704, f);
        }
        scal[i2] = v;
    }
}

// x [b][ic][h][w] (fp32 or bf16)  ->  xt [b][h][w][ic] bf16.
__global__ __launch_bounds__(256) void transpose_x(
        const void* __restrict__ x, const int* __restrict__ flag,
        u16* __restrict__ xt) {
    __shared__ u16 tbuf[32 * XP];
    const int b = blockIdx.z, h = blockIdx.y, w0 = blockIdx.x * 32;
    const int t = threadIdx.x;
    const int f = *flag;
    if (f) {
        const int w2 = t & 15, ic = t >> 4;
#pragma unroll
        for (int p = 0; p < 4; ++p) {
            int icc = ic + p * 16;
            const float* src = (const float*)x +
                (((size_t)(b * 64 + icc) * 128 + h) * 128 + w0 + 2 * w2);
            float2 v = *(const float2*)src;
            tbuf[(2 * w2) * XP + icc]     = f2bf(v.x);
            tbuf[(2 * w2 + 1) * XP + icc] = f2bf(v.y);
        }
    } else {
        const int w4 = t & 7, ic = t >> 3;
#pragma unroll
        for (int p = 0; p < 2; ++p) {
            int icc = ic + p * 32;
            const u16* src = (const u16*)x +
                (((size_t)(b * 64 + icc) * 128 + h) * 128 + w0 + 4 * w4);
            short4v v = *(const short4v*)src;
#pragma unroll
            for (int e = 0; e < 4; ++e)
                tbuf[(4 * w4 + e) * XP + icc] = (u16)v[e];
        }
    }
    __syncthreads();
    const int w = t >> 3, q = t & 7;
    short8 v = *(const short8*)&tbuf[w * XP + q * 8];
    *(short8*)(xt + ((size_t)((b * 128 + h) * 128) + w0 + w) * 64 + q * 8) = v;
}

// Virtual y3 values on the out-of-range frame.
// V[b][side][pos][oc]; pos-1 = coordinate along the side, in [-1,128].
// side 0: y3(-1, pos-1)  = b3 + sum_ic sum_c w3[2][c] * x(0,   pos-1+c-1)
// side 1: y3(128, pos-1) = b3 + sum_ic sum_c w3[0][c] * x(127, pos-1+c-1)
// side 2: y3(pos-1, -1)  = b3 + sum_ic sum_r w3[r][2] * x(pos-1+r-1, 0)
// side 3: y3(pos-1, 128) = b3 + sum_ic sum_r w3[r][0] * x(pos-1+r-1, 127)
__global__ __launch_bounds__(256) void virt_y3(
        const void* __restrict__ x, const void* __restrict__ w3,
        const float* __restrict__ scal, const int* __restrict__ flag,
        float* __restrict__ V) {
    const int side = blockIdx.x, b = blockIdx.y;
    const int t = threadIdx.x;
    const int f = *flag;
    const int oc = t & 63;
    const int pidx = blockIdx.z * 4 + (t >> 6);
    const float* b3f = scal + 704;
    const int fixed_rc = (side == 0) ? 0 : (side == 1 ? 127 : (side == 2 ? 0 : 127));
    const int ktap = (side == 0) ? 2 : (side == 1 ? 0 : (side == 2 ? 2 : 0));
    for (int pos = pidx; pos < 130; pos += 16) {
        int coord = pos - 1;   // varying coordinate of the virtual point
        float acc = b3f[oc];
        for (int ic = 0; ic < 64; ++ic) {
            const int wbase = (oc * 64 + ic) * 9;
#pragma unroll
            for (int kk = 0; kk < 3; ++kk) {
                int cc = coord + kk - 1;
                if ((unsigned)cc >= 128u) continue;
                float wv, xv;
                if (side < 2) {   // horizontal sides: kernel row ktap, col kk
                    wv = load_any(w3, wbase + ktap * 3 + kk, f);
                    xv = load_any(x, ((b * 64 + ic) * 128 + fixed_rc) * 128 + cc, f);
                } else {          // vertical sides: kernel row kk, col ktap
                    wv = load_any(w3, wbase + kk * 3 + ktap, f);
                    xv = load_any(x, ((b * 64 + ic) * 128 + cc) * 128 + fixed_rc, f);
                }
                acc = fmaf(wv, xv, acc);
            }
        }
        V[((size_t)(b * 4 + side) * 130 + pos) * 64 + oc] = acc;
    }
}

// Subtract clipped-shift composite contributions on the 1-px frame.
__global__ __launch_bounds__(256) void apply_fix(
        const float* __restrict__ V, const float* __restrict__ scal,
        const int* __restrict__ flag, void* __restrict__ out) {
    const int side = blockIdx.x, b = blockIdx.y;
    const int f = *flag;
    const float* wrf = scal + 64;
    const float* Vb = V + (size_t)b * 4 * 130 * 64;
    const float* VT = Vb;
    const float* VB = Vb + 130 * 64;
    const float* VL = Vb + 2 * 130 * 64;
    const float* VR = Vb + 3 * 130 * 64;
    const int nitems = (side < 2) ? 128 * 64 : 126 * 64;
    for (int idx = blockIdx.z * 256 + threadIdx.x; idx < nitems; idx += 512) {
        int oc = idx & 63;
        int h, w;
        if (side < 2) { w = idx >> 6; h = side ? 127 : 0; }
        else          { h = (idx >> 6) + 1; w = (side == 2) ? 0 : 127; }
        float s = 0.f;
#pragma unroll
        for (int sh = 0; sh < 3; ++sh)
#pragma unroll
            for (int sw = 0; sw < 3; ++sw) {
                int qh = h + 1 - sw, qw = w + 1 - sh;
                float v;
                if (qh == -1)       v = VT[(qw + 1) * 64 + oc];
                else if (qh == 128) v = VB[(qw + 1) * 64 + oc];
                else if (qw == -1)  v = VL[(qh + 1) * 64 + oc];
                else if (qw == 128) v = VR[(qh + 1) * 64 + oc];
                else continue;
                s -= wrf[oc * 10 + 1 + sh * 3 + sw] * v;
            }
        size_t oidx = ((size_t)(b * 64 + oc) * 128 + h) * 128 + w;
        if (f) ((float*)out)[oidx] += s;
        else {
            u16* po = (u16*)out + oidx;
            *po = f2bf(bf2f(*po) + s);
        }
    }
}

// Main: out = W5c (*) x + biasC.  16x16 px tile, 4 waves, acc[4 mt][4 nt].
// Weights double-buffered per tap (8 KB) in LDS via global_load_lds.
__global__ __launch_bounds__(256, 2) void conv_main(
        const u16* __restrict__ xt, const u16* __restrict__ w5c,
        const float* __restrict__ scal, const int* __restrict__ flag,
        void* __restrict__ out) {
    __shared__ __align__(16) u16 xs[400 * XP];         // 57600 B (20x20 halo)
    __shared__ __align__(16) u16 wbuf[2][2][2048];     // 16384 B
    const int b = blockIdx.z, h0 = blockIdx.y * 16, w0 = blockIdx.x * 16;
    const int tid = threadIdx.x;
    const int f = *flag;
    const int wv = tid >> 6, lane = tid & 63;

    // Stage x halo tile (coalesced b128 loads -> b128 LDS writes).
    {
        const int q8 = tid & 7, p0 = tid >> 3;
        for (int it = 0; it < 13; ++it) {
            int px = p0 + it * 32;
            if (px < 400) {
                int r = px / 20, c = px - r * 20;
                int gh = h0 + r - 2, gw = w0 + c - 2;
                short8 v = {0, 0, 0, 0, 0, 0, 0, 0};
                if ((unsigned)gh < 128u && (unsigned)gw < 128u)
                    v = *(const short8*)(xt +
                            ((size_t)((b * 128 + gh) * 128 + gw)) * 64 + q8 * 8);
                *(short8*)&xs[px * XP + q8 * 8] = v;
            }
        }
    }
    // Prologue: stage tap 0 weights.
    gl_lds16(w5c + 0 * 2048 + wv * 512 + lane * 8, &wbuf[0][0][wv * 512]);
    gl_lds16(w5c + 1 * 2048 + wv * 512 + lane * 8, &wbuf[0][1][wv * 512]);
    __syncthreads();

    const int cb = lane & 15, q = lane >> 4, wv4 = wv * 4;
    floatx4 acc[4][4];
#pragma unroll
    for (int mt = 0; mt < 4; ++mt)
#pragma unroll
        for (int nt = 0; nt < 4; ++nt)
            acc[mt][nt] = (floatx4){0.f, 0.f, 0.f, 0.f};

#pragma unroll 1
    for (int tap = 0; tap < 25; ++tap) {
        const int p = tap & 1;
        if (tap + 1 < 25) {   // prefetch next tap into other buffer
            gl_lds16(w5c + (size_t)((tap + 1) * 2 + 0) * 2048 + wv * 512 + lane * 8,
                     &wbuf[p ^ 1][0][wv * 512]);
            gl_lds16(w5c + (size_t)((tap + 1) * 2 + 1) * 2048 + wv * 512 + lane * 8,
                     &wbuf[p ^ 1][1][wv * 512]);
        }
        const int kh = tap / 5, kw = tap - kh * 5;
#pragma unroll
        for (int s = 0; s < 2; ++s) {
            short8 aa[4], bb[4];
#pragma unroll
            for (int mt = 0; mt < 4; ++mt)
                aa[mt] = *(const short8*)&wbuf[p][s][mt * 512 + lane * 8];
#pragma unroll
            for (int nt = 0; nt < 4; ++nt)
                bb[nt] = *(const short8*)&xs[((wv4 + nt + kh) * 20 + cb + kw) * XP +
                                             s * 32 + q * 8];
#pragma unroll
            for (int nt = 0; nt < 4; ++nt)
#pragma unroll
                for (int mt = 0; mt < 4; ++mt)
                    acc[mt][nt] = __builtin_amdgcn_mfma_f32_16x16x32_bf16(
                        aa[mt], bb[nt], acc[mt][nt], 0, 0, 0);
        }
        __syncthreads();   // wbuf[p] free for reuse; wbuf[p^1] writes complete
    }

    const float* biasC = scal;
#pragma unroll
    for (int mt = 0; mt < 4; ++mt)
#pragma unroll
        for (int nt = 0; nt < 4; ++nt) {
            int gh = h0 + wv4 + nt;
#pragma unroll
            for (int reg = 0; reg < 4; ++reg) {
                int oc = mt * 16 + q * 4 + reg;
                float s = acc[mt][nt][reg] + biasC[oc];
                size_t oidx = ((size_t)(b * 64 + oc) * 128 + gh) * 128 + w0 + cb;
                if (f) ((float*)out)[oidx] = s;
                else   ((u16*)out)[oidx]   = f2bf(s);
            }
        }
}

extern "C" void kernel_launch(void* const* d_in, const int* in_sizes, int n_in,
                              void* d_out, int out_size, void* d_ws, size_t ws_size,
                              hipStream_t stream) {
    const void* x  = d_in[0];
    const void* w3 = d_in[1];
    const void* b3 = d_in[2];
    const void* w5 = d_in[3];
    const void* b5 = d_in[4];
    const void* wr = d_in[5];
    const void* br = d_in[6];

    int*   flag = (int*)d_ws;
    u16*   w5c  = (u16*)((char*)d_ws + W5C_BYTE);
    float* scal = (float*)((char*)d_ws + SCAL_BYTE);
    float* V    = (float*)((char*)d_ws + V_BYTE);
    u16*   xt   = (u16*)((char*)d_ws + XT_BYTE);

    sniff_kernel<<<1, 256, 0, stream>>>((const u16*)x, flag);
    prepack<<<(PACK_N + 255) / 256, 256, 0, stream>>>(w3, b3, w5, b5, wr, br, flag,
                                                      w5c, scal);
    transpose_x<<<dim3(4, 128, 8), 256, 0, stream>>>(x, flag, xt);
    virt_y3<<<dim3(4, 8, 4), 256, 0, stream>>>(x, w3, scal, flag, V);
    conv_main<<<dim3(8, 8, 8), 256, 0, stream>>>(xt, w5c, scal, flag, d_out);
    apply_fix<<<dim3(4, 8, 2), 256, 0, stream>>>(V, scal, flag, d_out);
}

// Round 8
// 147.129 us; speedup vs baseline: 4.0120x; 4.0120x over previous
//
#include <hip/hip_runtime.h>

typedef unsigned short u16;
typedef unsigned int u32;
typedef __attribute__((ext_vector_type(8))) short short8;
typedef __attribute__((ext_vector_type(4))) short short4v;
typedef __attribute__((ext_vector_type(4))) float floatx4;

#define HH 128
#define WW 128
#define XP 72   // u16 pitch of px-major LDS tile (144 B, b128-aligned)

__device__ __forceinline__ float bf2f(u16 u) {
    u32 b = ((u32)u) << 16;
    return __builtin_bit_cast(float, b);
}
__device__ __forceinline__ u16 f2bf(float f) {
    u32 b = __builtin_bit_cast(u32, f);
    b += 0x7FFFu + ((b >> 16) & 1u);
    return (u16)(b >> 16);
}

typedef __attribute__((address_space(3))) u16 lds_u16;
typedef const __attribute__((address_space(1))) u16 glob_u16;
__device__ __forceinline__ void gl_lds16(const u16* g, u16* l) {
    __builtin_amdgcn_global_load_lds((glob_u16*)g, (lds_u16*)l, 16, 0, 0);
}

// ws layout (bytes):
//   [0,4)                 flag: 1 = fp32 inputs, 0 = bf16 inputs
//   [256, +204800)        w5c  bf16 A-frag (50 ks * 2048): composite 5x5 weights
//   [205056, +98304)      w3s  bf16 A-frag (4 sides * 6 ks * 2048): w3 side slices
//   [303360, +3072)       scal fp32: biasC[64], wr[640], b3[64]
//   [306432, +1064960)    V    fp32 [b][4][130][64]: virtual y3 frame values
//   [1371392, +16777216)  xt   bf16 [b][h][w][ic]
#define W5C_BYTE 256
#define W3S_BYTE 205056
#define SCAL_BYTE 303360
#define V_BYTE 306432
#define XT_BYTE 1371392
#define N_W5C 102400
#define N_W3S 49152
#define N_SCAL 768
#define PACK_N (N_W5C + N_W3S + N_SCAL)

__global__ __launch_bounds__(256) void sniff_kernel(const u16* __restrict__ xu,
                                                    int* __restrict__ flag) {
    __shared__ int cnt;
    if (threadIdx.x == 0) cnt = 0;
    __syncthreads();
    int c = 0;
    for (int k = 0; k < 8; ++k) {
        int idx = 2 * (threadIdx.x * 8 + k);
        u16 u = xu[idx];
        int e = (u >> 7) & 0xFF;
        if (e >= 140) c++;
    }
    atomicAdd(&cnt, c);
    __syncthreads();
    if (threadIdx.x == 0) *flag = (cnt >= 8) ? 1 : 0;
}

__device__ __forceinline__ float load_any(const void* p, int i, int isf32) {
    return isf32 ? ((const float*)p)[i] : bf2f(((const u16*)p)[i]);
}

// w5c: composite weights, A-frag order (see r6 comment).
// w3s: per-side w3 slices, A-frag order, K=192: k=kk*64+ic, side->(r,c):
//   side0 (top,   y3(-1,*)):  r=2, c=kk, x row 0
//   side1 (bot,   y3(128,*)): r=0, c=kk, x row 127
//   side2 (left,  y3(*,-1)):  r=kk, c=2, x col 0
//   side3 (right, y3(*,128)): r=kk, c=0, x col 127
__global__ __launch_bounds__(256) void prepack(
        const void* w3, const void* b3, const void* w5, const void* b5,
        const void* wr, const void* br, const int* __restrict__ flag,
        u16* __restrict__ w5c, u16* __restrict__ w3s, float* __restrict__ scal) {
    int i = blockIdx.x * 256 + threadIdx.x;
    if (i >= PACK_N) return;
    int f = *flag;
    if (i < N_W5C) {
        int j = i & 7, lane = (i >> 3) & 63, mt = (i >> 9) & 3, ks = i >> 11;
        int oc = mt * 16 + (lane & 15);
        int k = ks * 32 + ((lane >> 4) & 3) * 8 + j;
        int tap = k >> 6, ic = k & 63;
        int kh = tap / 5, kw = tap - kh * 5;
        int dh = kh - 2, dw = kw - 2;
        float v = load_any(wr, oc * 10, f) * load_any(w5, (oc * 64 + ic) * 25 + tap, f);
        for (int sw = 0; sw < 3; ++sw) {
            int r = dh + sw;
            if (r < 0 || r > 2) continue;
            for (int sh = 0; sh < 3; ++sh) {
                int c = dw + sh;
                if (c < 0 || c > 2) continue;
                v += load_any(wr, oc * 10 + 1 + sh * 3 + sw, f) *
                     load_any(w3, (oc * 64 + ic) * 9 + r * 3 + c, f);
            }
        }
        w5c[i] = f2bf(v);
    } else if (i < N_W5C + N_W3S) {
        int ii = i - N_W5C;
        int side = ii / 12288, rem = ii - side * 12288;
        int j = rem & 7, lane = (rem >> 3) & 63, mt = (rem >> 9) & 3, ks = rem >> 11;
        int oc = mt * 16 + (lane & 15);
        int k = ks * 32 + ((lane >> 4) & 3) * 8 + j;
        int kk = k >> 6, ic = k & 63;
        int r, c;
        if (side == 0)      { r = 2;  c = kk; }
        else if (side == 1) { r = 0;  c = kk; }
        else if (side == 2) { r = kk; c = 2;  }
        else                { r = kk; c = 0;  }
        w3s[ii] = f2bf(load_any(w3, (oc * 64 + ic) * 9 + r * 3 + c, f));
    } else {
        int i2 = i - N_W5C - N_W3S;
        float v;
        if (i2 < 64) {          // biasC
            int oc = i2;
            float swr = 0.f;
            for (int g = 1; g <= 9; ++g) swr += load_any(wr, oc * 10 + g, f);
            v = load_any(wr, oc * 10, f) * load_any(b5, oc, f) +
                swr * load_any(b3, oc, f) + load_any(br, oc, f);
        } else if (i2 < 704) {  // wr copy
            v = load_any(wr, i2 - 64, f);
        } else {                // b3 copy
            v = load_any(b3, i2 - 704, f);
        }
        scal[i2] = v;
    }
}

// x [b][ic][h][w] (fp32 or bf16)  ->  xt [b][h][w][ic] bf16.
__global__ __launch_bounds__(256) void transpose_x(
        const void* __restrict__ x, const int* __restrict__ flag,
        u16* __restrict__ xt) {
    __shared__ u16 tbuf[32 * XP];
    const int b = blockIdx.z, h = blockIdx.y, w0 = blockIdx.x * 32;
    const int t = threadIdx.x;
    const int f = *flag;
    if (f) {
        const int w2 = t & 15, ic = t >> 4;
#pragma unroll
        for (int p = 0; p < 4; ++p) {
            int icc = ic + p * 16;
            const float* src = (const float*)x +
                (((size_t)(b * 64 + icc) * 128 + h) * 128 + w0 + 2 * w2);
            float2 v = *(const float2*)src;
            tbuf[(2 * w2) * XP + icc]     = f2bf(v.x);
            tbuf[(2 * w2 + 1) * XP + icc] = f2bf(v.y);
        }
    } else {
        const int w4 = t & 7, ic = t >> 3;
#pragma unroll
        for (int p = 0; p < 2; ++p) {
            int icc = ic + p * 32;
            const u16* src = (const u16*)x +
                (((size_t)(b * 64 + icc) * 128 + h) * 128 + w0 + 4 * w4);
            short4v v = *(const short4v*)src;
#pragma unroll
            for (int e = 0; e < 4; ++e)
                tbuf[(4 * w4 + e) * XP + icc] = (u16)v[e];
        }
    }
    __syncthreads();
    const int w = t >> 3, q = t & 7;
    short8 v = *(const short8*)&tbuf[w * XP + q * 8];
    *(short8*)(xt + ((size_t)((b * 128 + h) * 128) + w0 + w) * 64 + q * 8) = v;
}

// Virtual y3 frame values via MFMA: per (side,b) one block.
// V[b][side][pos][oc] = b3[oc] + sum_{kk,ic} w3s[side][oc][kk*64+ic] *
//                        xrow[pos+kk][ic]   (xrow p = cc+2, cc = x coord)
__global__ __launch_bounds__(256) void virt_y3_mfma(
        const u16* __restrict__ xt, const u16* __restrict__ w3s,
        const float* __restrict__ scal, float* __restrict__ V) {
    __shared__ u16 xrow[146 * XP];   // rows 132..145 never written, never used
    const int side = blockIdx.x, b = blockIdx.y;
    const int tid = threadIdx.x;
    const int fixed = (side & 1) ? 127 : 0;
    {
        const int q8 = tid & 7, p0 = tid >> 3;
#pragma unroll
        for (int it = 0; it < 5; ++it) {
            int p = p0 + it * 32;
            if (p < 132) {
                int cc = p - 2;
                short8 v = {0, 0, 0, 0, 0, 0, 0, 0};
                if ((unsigned)cc < 128u) {
                    size_t idx = (side < 2)
                        ? ((size_t)(b * 128 + fixed) * 128 + cc)
                        : ((size_t)(b * 128 + cc) * 128 + fixed);
                    v = *(const short8*)(xt + idx * 64 + q8 * 8);
                }
                *(short8*)&xrow[p * XP + q8 * 8] = v;
            }
        }
    }
    __syncthreads();

    const int wv = tid >> 6, lane = tid & 63, cb = lane & 15, q = lane >> 4;
    floatx4 acc[9];
#pragma unroll
    for (int nt = 0; nt < 9; ++nt) acc[nt] = (floatx4){0.f, 0.f, 0.f, 0.f};

    const u16* wbase = w3s + side * 12288 + wv * 512 + lane * 8;
#pragma unroll
    for (int ks = 0; ks < 6; ++ks) {
        short8 aa = *(const short8*)(wbase + ks * 2048);
        const int kbase = ks * 32 + q * 8;
        const int kk = kbase >> 6, ic0 = kbase & 63;
#pragma unroll
        for (int nt = 0; nt < 9; ++nt) {
            int p = nt * 16 + cb + kk;     // may reach 145: reads junk, discarded
            short8 bb = *(const short8*)&xrow[p * XP + ic0];
            acc[nt] = __builtin_amdgcn_mfma_f32_16x16x32_bf16(aa, bb, acc[nt], 0, 0, 0);
        }
    }

    const float* b3f = scal + 704;
#pragma unroll
    for (int nt = 0; nt < 9; ++nt) {
        int pos = nt * 16 + cb;
        if (pos < 130) {
#pragma unroll
            for (int reg = 0; reg < 4; ++reg) {
                int oc = wv * 16 + q * 4 + reg;
                V[((size_t)(b * 4 + side) * 130 + pos) * 64 + oc] = acc[nt][reg] + b3f[oc];
            }
        }
    }
}

// Subtract clipped-shift composite contributions on the 1-px frame.
__global__ __launch_bounds__(256) void apply_fix(
        const float* __restrict__ V, const float* __restrict__ scal,
        const int* __restrict__ flag, void* __restrict__ out) {
    const int side = blockIdx.x, b = blockIdx.y;
    const int f = *flag;
    const float* wrf = scal + 64;
    const float* Vb = V + (size_t)b * 4 * 130 * 64;
    const float* VT = Vb;
    const float* VB = Vb + 130 * 64;
    const float* VL = Vb + 2 * 130 * 64;
    const float* VR = Vb + 3 * 130 * 64;
    const int nitems = (side < 2) ? 128 * 64 : 126 * 64;
    for (int idx = blockIdx.z * 256 + threadIdx.x; idx < nitems; idx += 2048) {
        int oc = idx & 63;
        int h, w;
        if (side < 2) { w = idx >> 6; h = side ? 127 : 0; }
        else          { h = (idx >> 6) + 1; w = (side == 2) ? 0 : 127; }
        float s = 0.f;
#pragma unroll
        for (int sh = 0; sh < 3; ++sh)
#pragma unroll
            for (int sw = 0; sw < 3; ++sw) {
                int qh = h + 1 - sw, qw = w + 1 - sh;
                float v;
                if (qh == -1)       v = VT[(qw + 1) * 64 + oc];
                else if (qh == 128) v = VB[(qw + 1) * 64 + oc];
                else if (qw == -1)  v = VL[(qh + 1) * 64 + oc];
                else if (qw == 128) v = VR[(qh + 1) * 64 + oc];
                else continue;
                s -= wrf[oc * 10 + 1 + sh * 3 + sw] * v;
            }
        size_t oidx = ((size_t)(b * 64 + oc) * 128 + h) * 128 + w;
        if (f) ((float*)out)[oidx] += s;
        else {
            u16* po = (u16*)out + oidx;
            *po = f2bf(bf2f(*po) + s);
        }
    }
}

// Main: out = W5c (*) x + biasC.  16x16 px tile, 4 waves, acc[4 mt][4 nt].
// Weights double-buffered per tap (8 KB) in LDS via global_load_lds.
__global__ __launch_bounds__(256, 2) void conv_main(
        const u16* __restrict__ xt, const u16* __restrict__ w5c,
        const float* __restrict__ scal, const int* __restrict__ flag,
        void* __restrict__ out) {
    __shared__ __align__(16) u16 xs[400 * XP];         // 57600 B (20x20 halo)
    __shared__ __align__(16) u16 wbuf[2][2][2048];     // 16384 B
    const int b = blockIdx.z, h0 = blockIdx.y * 16, w0 = blockIdx.x * 16;
    const int tid = threadIdx.x;
    const int f = *flag;
    const int wv = tid >> 6, lane = tid & 63;

    // Stage x halo tile (coalesced b128 loads -> b128 LDS writes).
    {
        const int q8 = tid & 7, p0 = tid >> 3;
        for (int it = 0; it < 13; ++it) {
            int px = p0 + it * 32;
            if (px < 400) {
                int r = px / 20, c = px - r * 20;
                int gh = h0 + r - 2, gw = w0 + c - 2;
                short8 v = {0, 0, 0, 0, 0, 0, 0, 0};
                if ((unsigned)gh < 128u && (unsigned)gw < 128u)
                    v = *(const short8*)(xt +
                            ((size_t)((b * 128 + gh) * 128 + gw)) * 64 + q8 * 8);
                *(short8*)&xs[px * XP + q8 * 8] = v;
            }
        }
    }
    // Prologue: stage tap 0 weights.
    gl_lds16(w5c + 0 * 2048 + wv * 512 + lane * 8, &wbuf[0][0][wv * 512]);
    gl_lds16(w5c + 1 * 2048 + wv * 512 + lane * 8, &wbuf[0][1][wv * 512]);
    __syncthreads();

    const int cb = lane & 15, q = lane >> 4, wv4 = wv * 4;
    floatx4 acc[4][4];
#pragma unroll
    for (int mt = 0; mt < 4; ++mt)
#pragma unroll
        for (int nt = 0; nt < 4; ++nt)
            acc[mt][nt] = (floatx4){0.f, 0.f, 0.f, 0.f};

#pragma unroll 1
    for (int tap = 0; tap < 25; ++tap) {
        const int p = tap & 1;
        if (tap + 1 < 25) {   // prefetch next tap into other buffer
            gl_lds16(w5c + (size_t)((tap + 1) * 2 + 0) * 2048 + wv * 512 + lane * 8,
                     &wbuf[p ^ 1][0][wv * 512]);
            gl_lds16(w5c + (size_t)((tap + 1) * 2 + 1) * 2048 + wv * 512 + lane * 8,
                     &wbuf[p ^ 1][1][wv * 512]);
        }
        const int kh = tap / 5, kw = tap - kh * 5;
#pragma unroll
        for (int s = 0; s < 2; ++s) {
            short8 aa[4], bb[4];
#pragma unroll
            for (int mt = 0; mt < 4; ++mt)
                aa[mt] = *(const short8*)&wbuf[p][s][mt * 512 + lane * 8];
#pragma unroll
            for (int nt = 0; nt < 4; ++nt)
                bb[nt] = *(const short8*)&xs[((wv4 + nt + kh) * 20 + cb + kw) * XP +
                                             s * 32 + q * 8];
#pragma unroll
            for (int nt = 0; nt < 4; ++nt)
#pragma unroll
                for (int mt = 0; mt < 4; ++mt)
                    acc[mt][nt] = __builtin_amdgcn_mfma_f32_16x16x32_bf16(
                        aa[mt], bb[nt], acc[mt][nt], 0, 0, 0);
        }
        __syncthreads();   // wbuf[p] free for reuse; wbuf[p^1] writes complete
    }

    const float* biasC = scal;
#pragma unroll
    for (int mt = 0; mt < 4; ++mt)
#pragma unroll
        for (int nt = 0; nt < 4; ++nt) {
            int gh = h0 + wv4 + nt;
#pragma unroll
            for (int reg = 0; reg < 4; ++reg) {
                int oc = mt * 16 + q * 4 + reg;
                float s = acc[mt][nt][reg] + biasC[oc];
                size_t oidx = ((size_t)(b * 64 + oc) * 128 + gh) * 128 + w0 + cb;
                if (f) ((float*)out)[oidx] = s;
                else   ((u16*)out)[oidx]   = f2bf(s);
            }
        }
}

extern "C" void kernel_launch(void* const* d_in, const int* in_sizes, int n_in,
                              void* d_out, int out_size, void* d_ws, size_t ws_size,
                              hipStream_t stream) {
    const void* x  = d_in[0];
    const void* w3 = d_in[1];
    const void* b3 = d_in[2];
    const void* w5 = d_in[3];
    const void* b5 = d_in[4];
    const void* wr = d_in[5];
    const void* br = d_in[6];

    int*   flag = (int*)d_ws;
    u16*   w5c  = (u16*)((char*)d_ws + W5C_BYTE);
    u16*   w3s  = (u16*)((char*)d_ws + W3S_BYTE);
    float* scal = (float*)((char*)d_ws + SCAL_BYTE);
    float* V    = (float*)((char*)d_ws + V_BYTE);
    u16*   xt   = (u16*)((char*)d_ws + XT_BYTE);

    sniff_kernel<<<1, 256, 0, stream>>>((const u16*)x, flag);
    prepack<<<(PACK_N + 255) / 256, 256, 0, stream>>>(w3, b3, w5, b5, wr, br, flag,
                                                      w5c, w3s, scal);
    transpose_x<<<dim3(4, 128, 8), 256, 0, stream>>>(x, flag, xt);
    virt_y3_mfma<<<dim3(4, 8), 256, 0, stream>>>(xt, w3s, scal, V);
    conv_main<<<dim3(8, 8, 8), 256, 0, stream>>>(xt, w5c, scal, flag, d_out);
    apply_fix<<<dim3(4, 8, 8), 256, 0, stream>>>(V, scal, flag, d_out);
}